// Round 4
// baseline (433.756 us; speedup 1.0000x reference)
//
#include <hip/hip_runtime.h>
#include <hip/hip_fp16.h>
#include <math.h>

#define SCALE 0.4082482904638631f   // 1/sqrt(6)

#define BATCH 8
#define HW    256
#define NPIX  65536

// ---------------- workspace layout ----------------
#define QKV_H_SIZE ((size_t)BATCH*144*NPIX)        // halves
#define VP_H_SIZE  ((size_t)BATCH*48*NPIX)         // halves
#define F_BYTE_OFF ((QKV_H_SIZE + VP_H_SIZE) * 2)  // byte offset of float region
#define GP_SIZE    (BATCH*32*8*48)                 // 98304 floats
#define M_SIZE     (BATCH*48*48)                   // 18432 floats
// float region: [gp][Mmat]

struct __align__(16) H8 { __half h[8]; };

typedef _Float16 f16x8 __attribute__((ext_vector_type(8)));
typedef float    f32x4 __attribute__((ext_vector_type(4)));

#define MFMA16(A,B,C) __builtin_amdgcn_mfma_f32_16x16x32_f16((A),(B),(C),0,0,0)

// ===========================================================================
// K_a (MFMA): 1x1 conv (48 -> 144) as GEMM [144x48]x[48x524288].
// Scalar-FMA versions were wedged at 130-150us (compiler regalloc: VGPR=40,
// 2x VALU bloat). MFMA makes this memory-bound: read x once (100.7 MB) +
// write qkv fp16 (147.5 MB) -> ~40us floor.
// Precision: hi/lo fp16 split of BOTH operands, c += Ah*Bh + Ah*Bl + Al*Bh
// (fp32 accum) -> residual ~2^-21 relative; only fp16 output rounding
// survives (same as previous rounds). K padded 48->64 with zeros on both
// A and B fragments.
// Layout (guide §3, m89-verified, dtype-independent):
//   A frag: row = l&15, k = (l>>4)*8 + j
//   B frag: col = l&15, k = (l>>4)*8 + j
//   C/D   : col = l&15, row = (l>>4)*4 + r
// Per block: 4 waves x 8 tiles x 16 px = 512 px. W staged once in LDS as
// prebuilt A fragments (hi+lo = 36 KB).
// ===========================================================================
__global__ __launch_bounds__(256) void ka_mfma(
    const float* __restrict__ x, const float* __restrict__ w1,
    __half* __restrict__ qkv)
{
  __shared__ __align__(16) _Float16 Alds[36 * 64 * 8];   // 36864 B

  const int tid = threadIdx.x;

  // ---- stage A fragments (hi at slot s, lo at slot 1152+s) ----
  for (int s = tid; s < 18 * 64; s += 256) {
    const int f  = s >> 6;          // frag id: m*2 + kf
    const int l  = s & 63;          // lane it will be read by
    const int m  = f >> 1;
    const int kf = f & 1;
    const int oc = m * 16 + (l & 15);
    const int kb = kf * 32 + (l >> 4) * 8;
    f16x8 ah, al;
    if (kf == 0 || (l >> 4) < 2) {          // k rows 0..47 real
      const float* wp8 = w1 + oc * 48 + kb; // w1: [oc][48] contiguous
#pragma unroll
      for (int j = 0; j < 8; ++j) {
        const float wv = wp8[j];
        const _Float16 h = (_Float16)wv;
        ah[j] = h;
        al[j] = (_Float16)(wv - (float)h);
      }
    } else {                                // k rows 48..63: zero pad
#pragma unroll
      for (int j = 0; j < 8; ++j) { ah[j] = (_Float16)0.0f; al[j] = (_Float16)0.0f; }
    }
    *(f16x8*)&Alds[(size_t)s * 8]          = ah;
    *(f16x8*)&Alds[(size_t)(1152 + s) * 8] = al;
  }
  __syncthreads();

  const int wv = tid >> 6;          // wave in block
  const int l  = tid & 63;          // lane
  const int px0 = blockIdx.x * 512 + wv * 128;
  const int b   = px0 >> 16;
  const int n0  = px0 & 65535;
  const float* xb = x   + ((size_t)b * 48)  * NPIX + n0 + (l & 15);
  __half*      ob = qkv + ((size_t)b * 144) * NPIX + n0 + (l & 15);
  const int kr   = (l >> 4) * 8;
  const bool blo = (l < 32);        // lanes whose B-frag1 k-rows are real

#pragma unroll 1
  for (int t = 0; t < 8; ++t) {
    const int coff = t * 16;

    // ---- load B column slices (fp32), build hi/lo fp16 fragments ----
    float xv0[8], xv1[8];
#pragma unroll
    for (int j = 0; j < 8; ++j) xv0[j] = xb[(size_t)(kr + j) * NPIX + coff];
    if (blo) {
#pragma unroll
      for (int j = 0; j < 8; ++j) xv1[j] = xb[(size_t)(32 + kr + j) * NPIX + coff];
    } else {
#pragma unroll
      for (int j = 0; j < 8; ++j) xv1[j] = 0.0f;
    }
    f16x8 bh0, bl0, bh1, bl1;
#pragma unroll
    for (int j = 0; j < 8; ++j) {
      const _Float16 h0 = (_Float16)xv0[j];
      bh0[j] = h0;
      bl0[j] = (_Float16)(xv0[j] - (float)h0);
      const _Float16 h1 = (_Float16)xv1[j];
      bh1[j] = h1;
      bl1[j] = (_Float16)(xv1[j] - (float)h1);
    }

    // ---- 9 M-tiles x (2 K-frags x 3 hi/lo terms) MFMA, store fp16 ----
#pragma unroll
    for (int m = 0; m < 9; ++m) {
      const int s0 = (m * 2 + 0) * 64 + l;
      const int s1 = (m * 2 + 1) * 64 + l;
      const f16x8 ah0 = *(const f16x8*)&Alds[(size_t)s0 * 8];
      const f16x8 al0 = *(const f16x8*)&Alds[(size_t)(1152 + s0) * 8];
      const f16x8 ah1 = *(const f16x8*)&Alds[(size_t)s1 * 8];
      const f16x8 al1 = *(const f16x8*)&Alds[(size_t)(1152 + s1) * 8];
      f32x4 c;
      c[0] = 0.0f; c[1] = 0.0f; c[2] = 0.0f; c[3] = 0.0f;
      c = MFMA16(ah0, bh0, c);
      c = MFMA16(ah0, bl0, c);
      c = MFMA16(al0, bh0, c);
      c = MFMA16(ah1, bh1, c);
      c = MFMA16(ah1, bl1, c);
      c = MFMA16(al1, bh1, c);
#pragma unroll
      for (int r = 0; r < 4; ++r)
        ob[(size_t)(m * 16 + (l >> 4) * 4 + r) * NPIX + coff] = __float2half(c[r]);
    }
  }
}

// ===========================================================================
// K_b_qk: per (b, head, 8-row band): stage 12 q/k channels x 10 rows x 256
// cols (fp16) in LDS via aligned dwordx4; dw-conv from LDS; accumulate 48
// gram values; block-reduce -> gram_part. LDS 63360 B -> 2 blocks/CU.
// ===========================================================================
__global__ __launch_bounds__(256, 2) void kb_qk(
    const __half* __restrict__ qkv, const float* __restrict__ wd,
    float* __restrict__ gram_part)
{
  __shared__ __align__(16) unsigned char smem[63360];
  __half* st  = (__half*)smem;               // [12][10][264]
  float*  red = (float*)smem;                // [256][52]  (aliased, after sync)
  float*  pr  = (float*)(smem + 53248);      // [192]

  const int blk  = blockIdx.x;
  const int band = blk & 31;
  const int h    = (blk >> 5) & 7;
  const int b    = blk >> 8;
  const int y0   = band * 8;
  const int tid  = threadIdx.x;
  const int g    = tid & 31;                 // col group (8 cols)
  const int rl   = tid >> 5;                 // out row 0..7
  const int x0   = g * 8;

  // ---- stage 12 channels x 10 rows ----
  const __half* qb = qkv + ((size_t)b * 144) * NPIX;
#pragma unroll
  for (int j = 0; j < 15; ++j) {
    const int cid = tid + j * 256;           // 0..3839
    const int ch  = cid / 320;
    const int rem = cid - ch * 320;
    const int r   = rem >> 5;
    const int c16 = rem & 31;
    const int gch = (ch < 6) ? (6 * h + ch) : (42 + 6 * h + ch);
    const int grow = y0 - 1 + r;
    H8 v;
    if ((unsigned)grow < 256u) {
      v = *(const H8*)(qb + (size_t)gch * NPIX + grow * 256 + c16 * 8);
    } else {
#pragma unroll
      for (int q = 0; q < 8; ++q) v.h[q] = __float2half(0.0f);
    }
    *(H8*)(st + (ch * 10 + r) * 264 + c16 * 8) = v;
  }
  __syncthreads();

  // ---- dw conv + gram ----
  auto dwrow = [&](int chslot, int gch, float o[8]) {
    const float* w9 = wd + gch * 9;
#pragma unroll
    for (int p = 0; p < 8; ++p) o[p] = 0.0f;
#pragma unroll
    for (int dr = 0; dr < 3; ++dr) {
      const __half* rowp = st + (chslot * 10 + rl + dr) * 264;
      float wn[10];
      wn[0] = (g > 0) ? __half2float(rowp[x0 - 1]) : 0.0f;
      const H8 m = *(const H8*)(rowp + x0);
#pragma unroll
      for (int q = 0; q < 8; ++q) wn[q + 1] = __half2float(m.h[q]);
      wn[9] = (g < 31) ? __half2float(rowp[x0 + 8]) : 0.0f;
#pragma unroll
      for (int dx = 0; dx < 3; ++dx) {
        const float wt = w9[dr * 3 + dx];
#pragma unroll
        for (int p = 0; p < 8; ++p) o[p] = fmaf(wt, wn[p + dx], o[p]);
      }
    }
  };

  float gram[48];
  float qv[6][8];
#pragma unroll
  for (int d = 0; d < 6; ++d) {
    dwrow(d, 6 * h + d, qv[d]);
    float s = 0.0f;
#pragma unroll
    for (int p = 0; p < 8; ++p) s = fmaf(qv[d][p], qv[d][p], s);
    gram[d] = s;
  }
#pragma unroll
  for (int e = 0; e < 6; ++e) {
    float kv[8];
    dwrow(6 + e, 48 + 6 * h + e, kv);
    float s = 0.0f;
#pragma unroll
    for (int p = 0; p < 8; ++p) s = fmaf(kv[p], kv[p], s);
    gram[6 + e] = s;
#pragma unroll
    for (int d = 0; d < 6; ++d) {
      float t = 0.0f;
#pragma unroll
      for (int p = 0; p < 8; ++p) t = fmaf(qv[d][p], kv[p], t);
      gram[12 + 6 * d + e] = t;
    }
  }
  __syncthreads();   // staging reads done; reuse smem as red

  float4* wrow4 = (float4*)(red + tid * 52);
#pragma unroll
  for (int j = 0; j < 12; ++j)
    wrow4[j] = make_float4(gram[4 * j], gram[4 * j + 1], gram[4 * j + 2], gram[4 * j + 3]);
  __syncthreads();

  if (tid < 192) {
    const int vv = tid >> 2, ch = tid & 3;
    float s = 0.0f;
    const float* base = red + (ch * 64) * 52 + vv;
    for (int p = 0; p < 64; ++p) s += base[p * 52];
    pr[vv * 4 + ch] = s;
  }
  __syncthreads();
  if (tid < 48)
    gram_part[(((size_t)b * 32 + band) * 8 + h) * 48 + tid] =
        pr[tid * 4] + pr[tid * 4 + 1] + pr[tid * 4 + 2] + pr[tid * 4 + 3];
}

// ===========================================================================
// K_b_v: per (b, v-channel, 32-row band): stage 34 rows x 256 cols fp16 in
// LDS; dw-conv from LDS; write fp16 v' (aligned 16-B stores).
// ===========================================================================
__global__ __launch_bounds__(256) void kb_v(
    const __half* __restrict__ qkv, const float* __restrict__ wd,
    __half* __restrict__ vp_ws)
{
  __shared__ __align__(16) __half st[34 * 264];

  const int blk  = blockIdx.x;
  const int band = blk & 7;
  const int ch   = (blk >> 3) % 48;
  const int b    = blk / (48 * 8);
  const int y0   = band * 32;
  const int tid  = threadIdx.x;
  const int g    = tid & 31;
  const int rl   = tid >> 5;
  const int x0   = g * 8;
  const int gch  = 96 + ch;

  const __half* plane = qkv + ((size_t)b * 144 + gch) * NPIX;
#pragma unroll
  for (int j = 0; j < 5; ++j) {
    const int cid = tid + j * 256;           // 0..1087
    if (cid < 1088) {
      const int r   = cid >> 5;
      const int c16 = cid & 31;
      const int grow = y0 - 1 + r;
      H8 v;
      if ((unsigned)grow < 256u) {
        v = *(const H8*)(plane + grow * 256 + c16 * 8);
      } else {
#pragma unroll
        for (int q = 0; q < 8; ++q) v.h[q] = __float2half(0.0f);
      }
      *(H8*)(st + r * 264 + c16 * 8) = v;
    }
  }
  __syncthreads();

  const float* w9 = wd + gch * 9;
  __half* outp = vp_ws + ((size_t)b * 48 + ch) * NPIX;
#pragma unroll
  for (int i = 0; i < 4; ++i) {
    const int r_out = rl + 8 * i;
    float o[8];
#pragma unroll
    for (int p = 0; p < 8; ++p) o[p] = 0.0f;
#pragma unroll
    for (int dr = 0; dr < 3; ++dr) {
      const __half* rowp = st + (r_out + dr) * 264;
      float wn[10];
      wn[0] = (g > 0) ? __half2float(rowp[x0 - 1]) : 0.0f;
      const H8 m = *(const H8*)(rowp + x0);
#pragma unroll
      for (int q = 0; q < 8; ++q) wn[q + 1] = __half2float(m.h[q]);
      wn[9] = (g < 31) ? __half2float(rowp[x0 + 8]) : 0.0f;
#pragma unroll
      for (int dx = 0; dx < 3; ++dx) {
        const float wt = w9[dr * 3 + dx];
#pragma unroll
        for (int p = 0; p < 8; ++p) o[p] = fmaf(wt, wn[p + dx], o[p]);
      }
    }
    H8 hv;
#pragma unroll
    for (int p = 0; p < 8; ++p) hv.h[p] = __float2half(o[p]);
    *(H8*)(outp + (y0 + r_out) * 256 + x0) = hv;
  }
}

// ===========================================================================
// K_d: per (b,head): sum 32 band partials -> norms -> softmax -> fold W_proj
// ===========================================================================
__global__ void kd_attn(const float* __restrict__ gram_part,
                        const float* __restrict__ wp, float* __restrict__ Mmat)
{
  const int b = blockIdx.x >> 3;
  const int h = blockIdx.x & 7;
  __shared__ float S[48];
  __shared__ float attn[36];
  const int tid = threadIdx.x;   // 64 threads

  if (tid < 48) {
    float s = 0.0f;
    for (int t = 0; t < 32; ++t)
      s += gram_part[(((size_t)b * 32 + t) * 8 + h) * 48 + tid];
    S[tid] = s;
  }
  __syncthreads();
  if (tid < 36) {
    const int d = tid / 6, e = tid - 6 * d;
    const float nq = fmaxf(sqrtf(S[d]),     1e-12f);
    const float nk = fmaxf(sqrtf(S[6 + e]), 1e-12f);
    attn[tid] = S[12 + tid] / (nq * nk) * SCALE;
  }
  __syncthreads();
  if (tid < 6) {
    float m = attn[tid * 6];
    for (int e = 1; e < 6; ++e) m = fmaxf(m, attn[tid * 6 + e]);
    float ex[6]; float sum = 0.0f;
    for (int e = 0; e < 6; ++e) { ex[e] = expf(attn[tid * 6 + e] - m); sum += ex[e]; }
    const float inv = 1.0f / sum;
    for (int e = 0; e < 6; ++e) attn[tid * 6 + e] = ex[e] * inv;
  }
  __syncthreads();
  for (int i = tid; i < 288; i += 64) {
    const int c = i / 6, e = i - 6 * (i / 6);
    float s = 0.0f;
#pragma unroll
    for (int d = 0; d < 6; ++d) s += wp[c * 48 + 6 * h + d] * attn[d * 6 + e];
    Mmat[((size_t)b * 48 + c) * 48 + 6 * h + e] = s;
  }
}

// ===========================================================================
// K_e: y[b][c][n] = sum_{c'} M_b[c][c'] * v'[b][c'][n]; 1 px/thread,
// vv[48] in VGPRs (spill-free at launch_bounds(256,4): 48+~16 < 128).
// ===========================================================================
__global__ __launch_bounds__(256, 4) void ke_out(
    const __half* __restrict__ vp_ws, const float* __restrict__ Mmat,
    float* __restrict__ y)
{
  const int b = blockIdx.x >> 8;
  const int n = ((blockIdx.x & 255) << 8) + threadIdx.x;
  const __half* vb = vp_ws + ((size_t)b * 48) * NPIX + n;
  const float* Mb = Mmat + (size_t)b * 2304;
  float vv[48];
#pragma unroll
  for (int c = 0; c < 48; ++c) vv[c] = __half2float(vb[(size_t)c * NPIX]);
  float* yb = y + ((size_t)b * 48) * NPIX + n;
#pragma unroll 4
  for (int c = 0; c < 48; ++c) {
    float s = 0.0f;
#pragma unroll
    for (int cc = 0; cc < 48; ++cc) s = fmaf(Mb[c * 48 + cc], vv[cc], s);
    yb[(size_t)c * NPIX] = s;
  }
}

// ===========================================================================
extern "C" void kernel_launch(void* const* d_in, const int* in_sizes, int n_in,
                              void* d_out, int out_size, void* d_ws, size_t ws_size,
                              hipStream_t stream)
{
  const float* x  = (const float*)d_in[0];
  const float* w1 = (const float*)d_in[1];   // (144,48,1,1)
  const float* wd = (const float*)d_in[2];   // (144,1,3,3)
  const float* wp = (const float*)d_in[3];   // (48,48,1,1)

  __half* qkv = (__half*)d_ws;
  __half* vp  = qkv + QKV_H_SIZE;
  float*  fw  = (float*)((char*)d_ws + F_BYTE_OFF);
  float*  gp   = fw;
  float*  Mmat = fw + GP_SIZE;

  hipLaunchKernelGGL(ka_mfma, dim3(1024), dim3(256), 0, stream, x, w1, qkv);
  hipLaunchKernelGGL(kb_qk,   dim3(2048), dim3(256), 0, stream, qkv, wd, gp);
  hipLaunchKernelGGL(kb_v,    dim3(3072), dim3(256), 0, stream, qkv, wd, vp);
  hipLaunchKernelGGL(kd_attn, dim3(64),   dim3(64),  0, stream, gp, wp, Mmat);
  hipLaunchKernelGGL(ke_out,  dim3(2048), dim3(256), 0, stream, vp, Mmat, (float*)d_out);
}

// Round 5
// 414.957 us; speedup vs baseline: 1.0453x; 1.0453x over previous
//
#include <hip/hip_runtime.h>
#include <hip/hip_fp16.h>
#include <math.h>

#define SCALE 0.4082482904638631f   // 1/sqrt(6)

#define BATCH 8
#define HW    256
#define NPIX  65536

// ---------------- workspace layout ----------------
#define QKV_H_SIZE ((size_t)BATCH*144*NPIX)        // halves
#define VP_H_SIZE  ((size_t)BATCH*48*NPIX)         // halves
#define F_BYTE_OFF ((QKV_H_SIZE + VP_H_SIZE) * 2)  // byte offset of float region
#define GP_SIZE    (BATCH*32*8*48)                 // 98304 floats
#define M_SIZE     (BATCH*48*48)                   // 18432 floats
// float region: [gp][Mmat]

struct __align__(16) H8 { __half h[8]; };

typedef _Float16 f16x8 __attribute__((ext_vector_type(8)));
typedef float    f32x4 __attribute__((ext_vector_type(4)));

#define MFMA16(A,B,C) __builtin_amdgcn_mfma_f32_16x16x32_f16((A),(B),(C),0,0,0)

// ===========================================================================
// K_a (MFMA): 1x1 conv (48 -> 144) as GEMM [144x48]x[48x524288].
// Round-4 version was latency-bound (MfmaUtil 7%, VALUBusy 10%, HBM 19% --
// every pipe idle): each tile iteration stalled vmcnt on its own x-loads
// before any compute. This version ping-pong prefetches: tile t+1's 16
// x-loads are issued BEFORE tile t's MFMA section, so the compiler's counted
// vmcnt wait lands after ~700 cyc of MFMA/ds_read/store work.
// Precision: hi/lo fp16 split of both operands, c += Ah*Bh + Ah*Bl + Al*Bh
// (fp32 accum); only the fp16 qkv-store rounding survives. K padded 48->64.
// Layout (guide §3, m89-verified):
//   A frag: row = l&15, k = (l>>4)*8 + j
//   B frag: col = l&15, k = (l>>4)*8 + j
//   C/D   : col = l&15, row = (l>>4)*4 + r
// ===========================================================================
__global__ __launch_bounds__(256) void ka_mfma(
    const float* __restrict__ x, const float* __restrict__ w1,
    __half* __restrict__ qkv)
{
  __shared__ __align__(16) _Float16 Alds[36 * 64 * 8];   // 36864 B

  const int tid = threadIdx.x;

  // ---- stage A fragments (hi at slot s, lo at slot 1152+s) ----
  for (int s = tid; s < 18 * 64; s += 256) {
    const int f  = s >> 6;          // frag id: m*2 + kf
    const int l  = s & 63;          // lane it will be read by
    const int m  = f >> 1;
    const int kf = f & 1;
    const int oc = m * 16 + (l & 15);
    const int kb = kf * 32 + (l >> 4) * 8;
    f16x8 ah, al;
    if (kf == 0 || (l >> 4) < 2) {          // k rows 0..47 real
      const float* wp8 = w1 + oc * 48 + kb; // w1: [oc][48] contiguous
#pragma unroll
      for (int j = 0; j < 8; ++j) {
        const float wv = wp8[j];
        const _Float16 h = (_Float16)wv;
        ah[j] = h;
        al[j] = (_Float16)(wv - (float)h);
      }
    } else {                                // k rows 48..63: zero pad
#pragma unroll
      for (int j = 0; j < 8; ++j) { ah[j] = (_Float16)0.0f; al[j] = (_Float16)0.0f; }
    }
    *(f16x8*)&Alds[(size_t)s * 8]          = ah;
    *(f16x8*)&Alds[(size_t)(1152 + s) * 8] = al;
  }
  __syncthreads();

  const int wv = tid >> 6;          // wave in block
  const int l  = tid & 63;          // lane
  const int px0 = blockIdx.x * 512 + wv * 128;
  const int b   = px0 >> 16;
  const int n0  = px0 & 65535;
  const float* xb = x   + ((size_t)b * 48)  * NPIX + n0 + (l & 15);
  __half*      ob = qkv + ((size_t)b * 144) * NPIX + n0 + (l & 15);
  const int kr   = (l >> 4) * 8;
  const bool blo = (l < 32);        // lanes whose B-frag1 k-rows are real

  // issue the 16 x-loads for tile t (no wait here; consumer waits counted)
  auto LOADX = [&](int t, float (&v0)[8], float (&v1)[8]) {
    const int coff = t * 16;
#pragma unroll
    for (int j = 0; j < 8; ++j) v0[j] = xb[(size_t)(kr + j) * NPIX + coff];
    if (blo) {
#pragma unroll
      for (int j = 0; j < 8; ++j) v1[j] = xb[(size_t)(32 + kr + j) * NPIX + coff];
    } else {
#pragma unroll
      for (int j = 0; j < 8; ++j) v1[j] = 0.0f;
    }
  };

  // fragment build + 9 M-tiles of (ds_read A, 6 MFMA, 4 stores)
  auto COMP = [&](int t, float (&v0)[8], float (&v1)[8]) {
    const int coff = t * 16;
    f16x8 bh0, bl0, bh1, bl1;
#pragma unroll
    for (int j = 0; j < 8; ++j) {
      const _Float16 h0 = (_Float16)v0[j];
      bh0[j] = h0;
      bl0[j] = (_Float16)(v0[j] - (float)h0);
      const _Float16 h1 = (_Float16)v1[j];
      bh1[j] = h1;
      bl1[j] = (_Float16)(v1[j] - (float)h1);
    }
#pragma unroll
    for (int m = 0; m < 9; ++m) {
      const int s0 = (m * 2 + 0) * 64 + l;
      const int s1 = (m * 2 + 1) * 64 + l;
      const f16x8 ah0 = *(const f16x8*)&Alds[(size_t)s0 * 8];
      const f16x8 al0 = *(const f16x8*)&Alds[(size_t)(1152 + s0) * 8];
      const f16x8 ah1 = *(const f16x8*)&Alds[(size_t)s1 * 8];
      const f16x8 al1 = *(const f16x8*)&Alds[(size_t)(1152 + s1) * 8];
      f32x4 c;
      c[0] = 0.0f; c[1] = 0.0f; c[2] = 0.0f; c[3] = 0.0f;
      c = MFMA16(ah0, bh0, c);
      c = MFMA16(ah0, bl0, c);
      c = MFMA16(al0, bh0, c);
      c = MFMA16(ah1, bh1, c);
      c = MFMA16(ah1, bl1, c);
      c = MFMA16(al1, bh1, c);
#pragma unroll
      for (int r = 0; r < 4; ++r)
        ob[(size_t)(m * 16 + (l >> 4) * 4 + r) * NPIX + coff] = __float2half(c[r]);
    }
  };

  float a0[8], a1[8], b0[8], b1[8];
  LOADX(0, a0, a1);
#pragma unroll 1
  for (int tt = 0; tt < 4; ++tt) {
    LOADX(2 * tt + 1, b0, b1);     // prefetch odd tile
    COMP(2 * tt, a0, a1);          // compute even tile (hides odd loads)
    if (tt < 3) LOADX(2 * tt + 2, a0, a1);  // prefetch next even tile
    COMP(2 * tt + 1, b0, b1);      // compute odd tile (hides even loads)
  }
}

// ===========================================================================
// K_b_qk: per (b, head, 8-row band): stage 12 q/k channels x 10 rows x 256
// cols (fp16) in LDS via aligned dwordx4; dw-conv from LDS; accumulate 48
// gram values; block-reduce -> gram_part. LDS 63360 B -> 2 blocks/CU.
// ===========================================================================
__global__ __launch_bounds__(256, 2) void kb_qk(
    const __half* __restrict__ qkv, const float* __restrict__ wd,
    float* __restrict__ gram_part)
{
  __shared__ __align__(16) unsigned char smem[63360];
  __half* st  = (__half*)smem;               // [12][10][264]
  float*  red = (float*)smem;                // [256][52]  (aliased, after sync)
  float*  pr  = (float*)(smem + 53248);      // [192]

  const int blk  = blockIdx.x;
  const int band = blk & 31;
  const int h    = (blk >> 5) & 7;
  const int b    = blk >> 8;
  const int y0   = band * 8;
  const int tid  = threadIdx.x;
  const int g    = tid & 31;                 // col group (8 cols)
  const int rl   = tid >> 5;                 // out row 0..7
  const int x0   = g * 8;

  // ---- stage 12 channels x 10 rows ----
  const __half* qb = qkv + ((size_t)b * 144) * NPIX;
#pragma unroll
  for (int j = 0; j < 15; ++j) {
    const int cid = tid + j * 256;           // 0..3839
    const int ch  = cid / 320;
    const int rem = cid - ch * 320;
    const int r   = rem >> 5;
    const int c16 = rem & 31;
    const int gch = (ch < 6) ? (6 * h + ch) : (42 + 6 * h + ch);
    const int grow = y0 - 1 + r;
    H8 v;
    if ((unsigned)grow < 256u) {
      v = *(const H8*)(qb + (size_t)gch * NPIX + grow * 256 + c16 * 8);
    } else {
#pragma unroll
      for (int q = 0; q < 8; ++q) v.h[q] = __float2half(0.0f);
    }
    *(H8*)(st + (ch * 10 + r) * 264 + c16 * 8) = v;
  }
  __syncthreads();

  // ---- dw conv + gram ----
  auto dwrow = [&](int chslot, int gch, float o[8]) {
    const float* w9 = wd + gch * 9;
#pragma unroll
    for (int p = 0; p < 8; ++p) o[p] = 0.0f;
#pragma unroll
    for (int dr = 0; dr < 3; ++dr) {
      const __half* rowp = st + (chslot * 10 + rl + dr) * 264;
      float wn[10];
      wn[0] = (g > 0) ? __half2float(rowp[x0 - 1]) : 0.0f;
      const H8 m = *(const H8*)(rowp + x0);
#pragma unroll
      for (int q = 0; q < 8; ++q) wn[q + 1] = __half2float(m.h[q]);
      wn[9] = (g < 31) ? __half2float(rowp[x0 + 8]) : 0.0f;
#pragma unroll
      for (int dx = 0; dx < 3; ++dx) {
        const float wt = w9[dr * 3 + dx];
#pragma unroll
        for (int p = 0; p < 8; ++p) o[p] = fmaf(wt, wn[p + dx], o[p]);
      }
    }
  };

  float gram[48];
  float qv[6][8];
#pragma unroll
  for (int d = 0; d < 6; ++d) {
    dwrow(d, 6 * h + d, qv[d]);
    float s = 0.0f;
#pragma unroll
    for (int p = 0; p < 8; ++p) s = fmaf(qv[d][p], qv[d][p], s);
    gram[d] = s;
  }
#pragma unroll
  for (int e = 0; e < 6; ++e) {
    float kv[8];
    dwrow(6 + e, 48 + 6 * h + e, kv);
    float s = 0.0f;
#pragma unroll
    for (int p = 0; p < 8; ++p) s = fmaf(kv[p], kv[p], s);
    gram[6 + e] = s;
#pragma unroll
    for (int d = 0; d < 6; ++d) {
      float t = 0.0f;
#pragma unroll
      for (int p = 0; p < 8; ++p) t = fmaf(qv[d][p], kv[p], t);
      gram[12 + 6 * d + e] = t;
    }
  }
  __syncthreads();   // staging reads done; reuse smem as red

  float4* wrow4 = (float4*)(red + tid * 52);
#pragma unroll
  for (int j = 0; j < 12; ++j)
    wrow4[j] = make_float4(gram[4 * j], gram[4 * j + 1], gram[4 * j + 2], gram[4 * j + 3]);
  __syncthreads();

  if (tid < 192) {
    const int vv = tid >> 2, ch = tid & 3;
    float s = 0.0f;
    const float* base = red + (ch * 64) * 52 + vv;
    for (int p = 0; p < 64; ++p) s += base[p * 52];
    pr[vv * 4 + ch] = s;
  }
  __syncthreads();
  if (tid < 48)
    gram_part[(((size_t)b * 32 + band) * 8 + h) * 48 + tid] =
        pr[tid * 4] + pr[tid * 4 + 1] + pr[tid * 4 + 2] + pr[tid * 4 + 3];
}

// ===========================================================================
// K_b_v: per (b, v-channel, 32-row band): stage 34 rows x 256 cols fp16 in
// LDS; dw-conv from LDS; write fp16 v' (aligned 16-B stores).
// ===========================================================================
__global__ __launch_bounds__(256) void kb_v(
    const __half* __restrict__ qkv, const float* __restrict__ wd,
    __half* __restrict__ vp_ws)
{
  __shared__ __align__(16) __half st[34 * 264];

  const int blk  = blockIdx.x;
  const int band = blk & 7;
  const int ch   = (blk >> 3) % 48;
  const int b    = blk / (48 * 8);
  const int y0   = band * 32;
  const int tid  = threadIdx.x;
  const int g    = tid & 31;
  const int rl   = tid >> 5;
  const int x0   = g * 8;
  const int gch  = 96 + ch;

  const __half* plane = qkv + ((size_t)b * 144 + gch) * NPIX;
#pragma unroll
  for (int j = 0; j < 5; ++j) {
    const int cid = tid + j * 256;           // 0..1087
    if (cid < 1088) {
      const int r   = cid >> 5;
      const int c16 = cid & 31;
      const int grow = y0 - 1 + r;
      H8 v;
      if ((unsigned)grow < 256u) {
        v = *(const H8*)(plane + grow * 256 + c16 * 8);
      } else {
#pragma unroll
        for (int q = 0; q < 8; ++q) v.h[q] = __float2half(0.0f);
      }
      *(H8*)(st + r * 264 + c16 * 8) = v;
    }
  }
  __syncthreads();

  const float* w9 = wd + gch * 9;
  __half* outp = vp_ws + ((size_t)b * 48 + ch) * NPIX;
#pragma unroll
  for (int i = 0; i < 4; ++i) {
    const int r_out = rl + 8 * i;
    float o[8];
#pragma unroll
    for (int p = 0; p < 8; ++p) o[p] = 0.0f;
#pragma unroll
    for (int dr = 0; dr < 3; ++dr) {
      const __half* rowp = st + (r_out + dr) * 264;
      float wn[10];
      wn[0] = (g > 0) ? __half2float(rowp[x0 - 1]) : 0.0f;
      const H8 m = *(const H8*)(rowp + x0);
#pragma unroll
      for (int q = 0; q < 8; ++q) wn[q + 1] = __half2float(m.h[q]);
      wn[9] = (g < 31) ? __half2float(rowp[x0 + 8]) : 0.0f;
#pragma unroll
      for (int dx = 0; dx < 3; ++dx) {
        const float wt = w9[dr * 3 + dx];
#pragma unroll
        for (int p = 0; p < 8; ++p) o[p] = fmaf(wt, wn[p + dx], o[p]);
      }
    }
    H8 hv;
#pragma unroll
    for (int p = 0; p < 8; ++p) hv.h[p] = __float2half(o[p]);
    *(H8*)(outp + (y0 + r_out) * 256 + x0) = hv;
  }
}

// ===========================================================================
// K_d: per (b,head): sum 32 band partials -> norms -> softmax -> fold W_proj
// ===========================================================================
__global__ void kd_attn(const float* __restrict__ gram_part,
                        const float* __restrict__ wp, float* __restrict__ Mmat)
{
  const int b = blockIdx.x >> 3;
  const int h = blockIdx.x & 7;
  __shared__ float S[48];
  __shared__ float attn[36];
  const int tid = threadIdx.x;   // 64 threads

  if (tid < 48) {
    float s = 0.0f;
    for (int t = 0; t < 32; ++t)
      s += gram_part[(((size_t)b * 32 + t) * 8 + h) * 48 + tid];
    S[tid] = s;
  }
  __syncthreads();
  if (tid < 36) {
    const int d = tid / 6, e = tid - 6 * d;
    const float nq = fmaxf(sqrtf(S[d]),     1e-12f);
    const float nk = fmaxf(sqrtf(S[6 + e]), 1e-12f);
    attn[tid] = S[12 + tid] / (nq * nk) * SCALE;
  }
  __syncthreads();
  if (tid < 6) {
    float m = attn[tid * 6];
    for (int e = 1; e < 6; ++e) m = fmaxf(m, attn[tid * 6 + e]);
    float ex[6]; float sum = 0.0f;
    for (int e = 0; e < 6; ++e) { ex[e] = expf(attn[tid * 6 + e] - m); sum += ex[e]; }
    const float inv = 1.0f / sum;
    for (int e = 0; e < 6; ++e) attn[tid * 6 + e] = ex[e] * inv;
  }
  __syncthreads();
  for (int i = tid; i < 288; i += 64) {
    const int c = i / 6, e = i - 6 * (i / 6);
    float s = 0.0f;
#pragma unroll
    for (int d = 0; d < 6; ++d) s += wp[c * 48 + 6 * h + d] * attn[d * 6 + e];
    Mmat[((size_t)b * 48 + c) * 48 + 6 * h + e] = s;
  }
}

// ===========================================================================
// K_e: y[b][c][n] = sum_{c'} M_b[c][c'] * v'[b][c'][n]; 1 px/thread,
// vv[48] in VGPRs (spill-free at launch_bounds(256,4): 48+~16 < 128).
// ===========================================================================
__global__ __launch_bounds__(256, 4) void ke_out(
    const __half* __restrict__ vp_ws, const float* __restrict__ Mmat,
    float* __restrict__ y)
{
  const int b = blockIdx.x >> 8;
  const int n = ((blockIdx.x & 255) << 8) + threadIdx.x;
  const __half* vb = vp_ws + ((size_t)b * 48) * NPIX + n;
  const float* Mb = Mmat + (size_t)b * 2304;
  float vv[48];
#pragma unroll
  for (int c = 0; c < 48; ++c) vv[c] = __half2float(vb[(size_t)c * NPIX]);
  float* yb = y + ((size_t)b * 48) * NPIX + n;
#pragma unroll 4
  for (int c = 0; c < 48; ++c) {
    float s = 0.0f;
#pragma unroll
    for (int cc = 0; cc < 48; ++cc) s = fmaf(Mb[c * 48 + cc], vv[cc], s);
    yb[(size_t)c * NPIX] = s;
  }
}

// ===========================================================================
extern "C" void kernel_launch(void* const* d_in, const int* in_sizes, int n_in,
                              void* d_out, int out_size, void* d_ws, size_t ws_size,
                              hipStream_t stream)
{
  const float* x  = (const float*)d_in[0];
  const float* w1 = (const float*)d_in[1];   // (144,48,1,1)
  const float* wd = (const float*)d_in[2];   // (144,1,3,3)
  const float* wp = (const float*)d_in[3];   // (48,48,1,1)

  __half* qkv = (__half*)d_ws;
  __half* vp  = qkv + QKV_H_SIZE;
  float*  fw  = (float*)((char*)d_ws + F_BYTE_OFF);
  float*  gp   = fw;
  float*  Mmat = fw + GP_SIZE;

  hipLaunchKernelGGL(ka_mfma, dim3(1024), dim3(256), 0, stream, x, w1, qkv);
  hipLaunchKernelGGL(kb_qk,   dim3(2048), dim3(256), 0, stream, qkv, wd, gp);
  hipLaunchKernelGGL(kb_v,    dim3(3072), dim3(256), 0, stream, qkv, wd, vp);
  hipLaunchKernelGGL(kd_attn, dim3(64),   dim3(64),  0, stream, gp, wp, Mmat);
  hipLaunchKernelGGL(ke_out,  dim3(2048), dim3(256), 0, stream, vp, Mmat, (float*)d_out);
}

// Round 6
// 361.079 us; speedup vs baseline: 1.2013x; 1.1492x over previous
//
#include <hip/hip_runtime.h>
#include <hip/hip_fp16.h>
#include <math.h>

#define SCALE 0.4082482904638631f   // 1/sqrt(6)

#define BATCH 8
#define HW    256
#define NPIX  65536

// ---------------- workspace layout ----------------
#define QKV_H_SIZE ((size_t)BATCH*144*NPIX)        // halves
#define VP_H_SIZE  ((size_t)BATCH*48*NPIX)         // halves
#define F_BYTE_OFF ((QKV_H_SIZE + VP_H_SIZE) * 2)  // byte offset of float region
#define GP_SIZE    (BATCH*32*8*48)                 // 98304 floats
#define M_SIZE     (BATCH*48*48)                   // 18432 floats
// float region: [gp][Mmat]

struct __align__(16) H8 { __half h[8]; };

typedef _Float16 f16x8 __attribute__((ext_vector_type(8)));
typedef float    f32x4 __attribute__((ext_vector_type(4)));

#define MFMA16(A,B,C) __builtin_amdgcn_mfma_f32_16x16x32_f16((A),(B),(C),0,0,0)

// ===========================================================================
// K_a (MFMA): 1x1 conv (48 -> 144) as GEMM [144x48]x[48x524288].
// Round-5 post-mortem: ILP-style prefetch left every pipe idle (MfmaUtil 8%,
// VALU 11%, HBM 25%) because occupancy collapsed to ~10% (VGPR 152, grid
// 1024, long serial 8-tile chains). This version trades ILP for TLP:
// grid 4096, 2 tiles/wave, launch_bounds(256,6) (VGPR<=85). Residency is
// then LDS-capped at 4 blocks/CU = 16 waves/CU (50%), with 16 blocks/CU of
// queued work. Latency hiding comes from co-resident waves (the mechanism
// the chip actually rewards, per m114/m131), not software pipelining.
// Precision: hi/lo fp16 split of both operands, c += Ah*Bh + Ah*Bl + Al*Bh
// (fp32 accum); only the fp16 qkv-store rounding survives. K padded 48->64.
// Layout (guide §3, m89-verified):
//   A frag: row = l&15, k = (l>>4)*8 + j
//   B frag: col = l&15, k = (l>>4)*8 + j
//   C/D   : col = l&15, row = (l>>4)*4 + r
// ===========================================================================
__global__ __launch_bounds__(256, 6) void ka_mfma(
    const float* __restrict__ x, const float* __restrict__ w1,
    __half* __restrict__ qkv)
{
  __shared__ __align__(16) _Float16 Alds[36 * 64 * 8];   // 36864 B

  const int tid = threadIdx.x;

  // ---- stage A fragments (hi at slot s, lo at slot 1152+s) ----
  for (int s = tid; s < 18 * 64; s += 256) {
    const int f  = s >> 6;          // frag id: m*2 + kf
    const int l  = s & 63;          // lane it will be read by
    const int m  = f >> 1;
    const int kf = f & 1;
    const int oc = m * 16 + (l & 15);
    const int kb = kf * 32 + (l >> 4) * 8;
    f16x8 ah, al;
    if (kf == 0 || (l >> 4) < 2) {          // k rows 0..47 real
      const float* wp8 = w1 + oc * 48 + kb; // w1: [oc][48] contiguous
#pragma unroll
      for (int j = 0; j < 8; ++j) {
        const float wv = wp8[j];
        const _Float16 h = (_Float16)wv;
        ah[j] = h;
        al[j] = (_Float16)(wv - (float)h);
      }
    } else {                                // k rows 48..63: zero pad
#pragma unroll
      for (int j = 0; j < 8; ++j) { ah[j] = (_Float16)0.0f; al[j] = (_Float16)0.0f; }
    }
    *(f16x8*)&Alds[(size_t)s * 8]          = ah;
    *(f16x8*)&Alds[(size_t)(1152 + s) * 8] = al;
  }
  __syncthreads();

  const int wv = tid >> 6;          // wave in block
  const int l  = tid & 63;          // lane
  const int px0 = blockIdx.x * 128 + wv * 32;   // 32 px per wave (2 tiles)
  const int b   = px0 >> 16;
  const int n0  = px0 & 65535;
  const float* xb = x   + ((size_t)b * 48)  * NPIX + n0 + (l & 15);
  __half*      ob = qkv + ((size_t)b * 144) * NPIX + n0 + (l & 15);
  const int kr   = (l >> 4) * 8;
  const bool blo = (l < 32);        // lanes whose B-frag1 k-rows are real

#pragma unroll 1
  for (int t = 0; t < 2; ++t) {
    const int coff = t * 16;

    // ---- load B column slices (fp32), build hi/lo fp16 fragments ----
    float xv0[8], xv1[8];
#pragma unroll
    for (int j = 0; j < 8; ++j) xv0[j] = xb[(size_t)(kr + j) * NPIX + coff];
    if (blo) {
#pragma unroll
      for (int j = 0; j < 8; ++j) xv1[j] = xb[(size_t)(32 + kr + j) * NPIX + coff];
    } else {
#pragma unroll
      for (int j = 0; j < 8; ++j) xv1[j] = 0.0f;
    }
    f16x8 bh0, bl0, bh1, bl1;
#pragma unroll
    for (int j = 0; j < 8; ++j) {
      const _Float16 h0 = (_Float16)xv0[j];
      bh0[j] = h0;
      bl0[j] = (_Float16)(xv0[j] - (float)h0);
      const _Float16 h1 = (_Float16)xv1[j];
      bh1[j] = h1;
      bl1[j] = (_Float16)(xv1[j] - (float)h1);
    }

    // ---- 9 M-tiles x (2 K-frags x 3 hi/lo terms) MFMA, store fp16 ----
#pragma unroll
    for (int m = 0; m < 9; ++m) {
      const int s0 = (m * 2 + 0) * 64 + l;
      const int s1 = (m * 2 + 1) * 64 + l;
      const f16x8 ah0 = *(const f16x8*)&Alds[(size_t)s0 * 8];
      const f16x8 al0 = *(const f16x8*)&Alds[(size_t)(1152 + s0) * 8];
      const f16x8 ah1 = *(const f16x8*)&Alds[(size_t)s1 * 8];
      const f16x8 al1 = *(const f16x8*)&Alds[(size_t)(1152 + s1) * 8];
      f32x4 c;
      c[0] = 0.0f; c[1] = 0.0f; c[2] = 0.0f; c[3] = 0.0f;
      c = MFMA16(ah0, bh0, c);
      c = MFMA16(ah0, bl0, c);
      c = MFMA16(al0, bh0, c);
      c = MFMA16(ah1, bh1, c);
      c = MFMA16(ah1, bl1, c);
      c = MFMA16(al1, bh1, c);
#pragma unroll
      for (int r = 0; r < 4; ++r)
        ob[(size_t)(m * 16 + (l >> 4) * 4 + r) * NPIX + coff] = __float2half(c[r]);
    }
  }
}

// ===========================================================================
// K_b_qk: per (b, head, 8-row band): stage 12 q/k channels x 10 rows x 256
// cols (fp16) in LDS via aligned dwordx4; dw-conv from LDS; accumulate 48
// gram values; block-reduce -> gram_part. LDS 63360 B -> 2 blocks/CU.
// ===========================================================================
__global__ __launch_bounds__(256, 2) void kb_qk(
    const __half* __restrict__ qkv, const float* __restrict__ wd,
    float* __restrict__ gram_part)
{
  __shared__ __align__(16) unsigned char smem[63360];
  __half* st  = (__half*)smem;               // [12][10][264]
  float*  red = (float*)smem;                // [256][52]  (aliased, after sync)
  float*  pr  = (float*)(smem + 53248);      // [192]

  const int blk  = blockIdx.x;
  const int band = blk & 31;
  const int h    = (blk >> 5) & 7;
  const int b    = blk >> 8;
  const int y0   = band * 8;
  const int tid  = threadIdx.x;
  const int g    = tid & 31;                 // col group (8 cols)
  const int rl   = tid >> 5;                 // out row 0..7
  const int x0   = g * 8;

  // ---- stage 12 channels x 10 rows ----
  const __half* qb = qkv + ((size_t)b * 144) * NPIX;
#pragma unroll
  for (int j = 0; j < 15; ++j) {
    const int cid = tid + j * 256;           // 0..3839
    const int ch  = cid / 320;
    const int rem = cid - ch * 320;
    const int r   = rem >> 5;
    const int c16 = rem & 31;
    const int gch = (ch < 6) ? (6 * h + ch) : (42 + 6 * h + ch);
    const int grow = y0 - 1 + r;
    H8 v;
    if ((unsigned)grow < 256u) {
      v = *(const H8*)(qb + (size_t)gch * NPIX + grow * 256 + c16 * 8);
    } else {
#pragma unroll
      for (int q = 0; q < 8; ++q) v.h[q] = __float2half(0.0f);
    }
    *(H8*)(st + (ch * 10 + r) * 264 + c16 * 8) = v;
  }
  __syncthreads();

  // ---- dw conv + gram ----
  auto dwrow = [&](int chslot, int gch, float o[8]) {
    const float* w9 = wd + gch * 9;
#pragma unroll
    for (int p = 0; p < 8; ++p) o[p] = 0.0f;
#pragma unroll
    for (int dr = 0; dr < 3; ++dr) {
      const __half* rowp = st + (chslot * 10 + rl + dr) * 264;
      float wn[10];
      wn[0] = (g > 0) ? __half2float(rowp[x0 - 1]) : 0.0f;
      const H8 m = *(const H8*)(rowp + x0);
#pragma unroll
      for (int q = 0; q < 8; ++q) wn[q + 1] = __half2float(m.h[q]);
      wn[9] = (g < 31) ? __half2float(rowp[x0 + 8]) : 0.0f;
#pragma unroll
      for (int dx = 0; dx < 3; ++dx) {
        const float wt = w9[dr * 3 + dx];
#pragma unroll
        for (int p = 0; p < 8; ++p) o[p] = fmaf(wt, wn[p + dx], o[p]);
      }
    }
  };

  float gram[48];
  float qv[6][8];
#pragma unroll
  for (int d = 0; d < 6; ++d) {
    dwrow(d, 6 * h + d, qv[d]);
    float s = 0.0f;
#pragma unroll
    for (int p = 0; p < 8; ++p) s = fmaf(qv[d][p], qv[d][p], s);
    gram[d] = s;
  }
#pragma unroll
  for (int e = 0; e < 6; ++e) {
    float kv[8];
    dwrow(6 + e, 48 + 6 * h + e, kv);
    float s = 0.0f;
#pragma unroll
    for (int p = 0; p < 8; ++p) s = fmaf(kv[p], kv[p], s);
    gram[6 + e] = s;
#pragma unroll
    for (int d = 0; d < 6; ++d) {
      float t = 0.0f;
#pragma unroll
      for (int p = 0; p < 8; ++p) t = fmaf(qv[d][p], kv[p], t);
      gram[12 + 6 * d + e] = t;
    }
  }
  __syncthreads();   // staging reads done; reuse smem as red

  float4* wrow4 = (float4*)(red + tid * 52);
#pragma unroll
  for (int j = 0; j < 12; ++j)
    wrow4[j] = make_float4(gram[4 * j], gram[4 * j + 1], gram[4 * j + 2], gram[4 * j + 3]);
  __syncthreads();

  if (tid < 192) {
    const int vv = tid >> 2, ch = tid & 3;
    float s = 0.0f;
    const float* base = red + (ch * 64) * 52 + vv;
    for (int p = 0; p < 64; ++p) s += base[p * 52];
    pr[vv * 4 + ch] = s;
  }
  __syncthreads();
  if (tid < 48)
    gram_part[(((size_t)b * 32 + band) * 8 + h) * 48 + tid] =
        pr[tid * 4] + pr[tid * 4 + 1] + pr[tid * 4 + 2] + pr[tid * 4 + 3];
}

// ===========================================================================
// K_b_v: per (b, v-channel, 32-row band): stage 34 rows x 256 cols fp16 in
// LDS; dw-conv from LDS; write fp16 v' (aligned 16-B stores).
// ===========================================================================
__global__ __launch_bounds__(256) void kb_v(
    const __half* __restrict__ qkv, const float* __restrict__ wd,
    __half* __restrict__ vp_ws)
{
  __shared__ __align__(16) __half st[34 * 264];

  const int blk  = blockIdx.x;
  const int band = blk & 7;
  const int ch   = (blk >> 3) % 48;
  const int b    = blk / (48 * 8);
  const int y0   = band * 32;
  const int tid  = threadIdx.x;
  const int g    = tid & 31;
  const int rl   = tid >> 5;
  const int x0   = g * 8;
  const int gch  = 96 + ch;

  const __half* plane = qkv + ((size_t)b * 144 + gch) * NPIX;
#pragma unroll
  for (int j = 0; j < 5; ++j) {
    const int cid = tid + j * 256;           // 0..1087
    if (cid < 1088) {
      const int r   = cid >> 5;
      const int c16 = cid & 31;
      const int grow = y0 - 1 + r;
      H8 v;
      if ((unsigned)grow < 256u) {
        v = *(const H8*)(plane + grow * 256 + c16 * 8);
      } else {
#pragma unroll
        for (int q = 0; q < 8; ++q) v.h[q] = __float2half(0.0f);
      }
      *(H8*)(st + r * 264 + c16 * 8) = v;
    }
  }
  __syncthreads();

  const float* w9 = wd + gch * 9;
  __half* outp = vp_ws + ((size_t)b * 48 + ch) * NPIX;
#pragma unroll
  for (int i = 0; i < 4; ++i) {
    const int r_out = rl + 8 * i;
    float o[8];
#pragma unroll
    for (int p = 0; p < 8; ++p) o[p] = 0.0f;
#pragma unroll
    for (int dr = 0; dr < 3; ++dr) {
      const __half* rowp = st + (r_out + dr) * 264;
      float wn[10];
      wn[0] = (g > 0) ? __half2float(rowp[x0 - 1]) : 0.0f;
      const H8 m = *(const H8*)(rowp + x0);
#pragma unroll
      for (int q = 0; q < 8; ++q) wn[q + 1] = __half2float(m.h[q]);
      wn[9] = (g < 31) ? __half2float(rowp[x0 + 8]) : 0.0f;
#pragma unroll
      for (int dx = 0; dx < 3; ++dx) {
        const float wt = w9[dr * 3 + dx];
#pragma unroll
        for (int p = 0; p < 8; ++p) o[p] = fmaf(wt, wn[p + dx], o[p]);
      }
    }
    H8 hv;
#pragma unroll
    for (int p = 0; p < 8; ++p) hv.h[p] = __float2half(o[p]);
    *(H8*)(outp + (y0 + r_out) * 256 + x0) = hv;
  }
}

// ===========================================================================
// K_d: per (b,head): sum 32 band partials -> norms -> softmax -> fold W_proj
// ===========================================================================
__global__ void kd_attn(const float* __restrict__ gram_part,
                        const float* __restrict__ wp, float* __restrict__ Mmat)
{
  const int b = blockIdx.x >> 3;
  const int h = blockIdx.x & 7;
  __shared__ float S[48];
  __shared__ float attn[36];
  const int tid = threadIdx.x;   // 64 threads

  if (tid < 48) {
    float s = 0.0f;
    for (int t = 0; t < 32; ++t)
      s += gram_part[(((size_t)b * 32 + t) * 8 + h) * 48 + tid];
    S[tid] = s;
  }
  __syncthreads();
  if (tid < 36) {
    const int d = tid / 6, e = tid - 6 * d;
    const float nq = fmaxf(sqrtf(S[d]),     1e-12f);
    const float nk = fmaxf(sqrtf(S[6 + e]), 1e-12f);
    attn[tid] = S[12 + tid] / (nq * nk) * SCALE;
  }
  __syncthreads();
  if (tid < 6) {
    float m = attn[tid * 6];
    for (int e = 1; e < 6; ++e) m = fmaxf(m, attn[tid * 6 + e]);
    float ex[6]; float sum = 0.0f;
    for (int e = 0; e < 6; ++e) { ex[e] = expf(attn[tid * 6 + e] - m); sum += ex[e]; }
    const float inv = 1.0f / sum;
    for (int e = 0; e < 6; ++e) attn[tid * 6 + e] = ex[e] * inv;
  }
  __syncthreads();
  for (int i = tid; i < 288; i += 64) {
    const int c = i / 6, e = i - 6 * (i / 6);
    float s = 0.0f;
#pragma unroll
    for (int d = 0; d < 6; ++d) s += wp[c * 48 + 6 * h + d] * attn[d * 6 + e];
    Mmat[((size_t)b * 48 + c) * 48 + 6 * h + e] = s;
  }
}

// ===========================================================================
// K_e: y[b][c][n] = sum_{c'} M_b[c][c'] * v'[b][c'][n]; 1 px/thread,
// vv[48] in VGPRs (spill-free at launch_bounds(256,4): 48+~16 < 128).
// ===========================================================================
__global__ __launch_bounds__(256, 4) void ke_out(
    const __half* __restrict__ vp_ws, const float* __restrict__ Mmat,
    float* __restrict__ y)
{
  const int b = blockIdx.x >> 8;
  const int n = ((blockIdx.x & 255) << 8) + threadIdx.x;
  const __half* vb = vp_ws + ((size_t)b * 48) * NPIX + n;
  const float* Mb = Mmat + (size_t)b * 2304;
  float vv[48];
#pragma unroll
  for (int c = 0; c < 48; ++c) vv[c] = __half2float(vb[(size_t)c * NPIX]);
  float* yb = y + ((size_t)b * 48) * NPIX + n;
#pragma unroll 4
  for (int c = 0; c < 48; ++c) {
    float s = 0.0f;
#pragma unroll
    for (int cc = 0; cc < 48; ++cc) s = fmaf(Mb[c * 48 + cc], vv[cc], s);
    yb[(size_t)c * NPIX] = s;
  }
}

// ===========================================================================
extern "C" void kernel_launch(void* const* d_in, const int* in_sizes, int n_in,
                              void* d_out, int out_size, void* d_ws, size_t ws_size,
                              hipStream_t stream)
{
  const float* x  = (const float*)d_in[0];
  const float* w1 = (const float*)d_in[1];   // (144,48,1,1)
  const float* wd = (const float*)d_in[2];   // (144,1,3,3)
  const float* wp = (const float*)d_in[3];   // (48,48,1,1)

  __half* qkv = (__half*)d_ws;
  __half* vp  = qkv + QKV_H_SIZE;
  float*  fw  = (float*)((char*)d_ws + F_BYTE_OFF);
  float*  gp   = fw;
  float*  Mmat = fw + GP_SIZE;

  hipLaunchKernelGGL(ka_mfma, dim3(4096), dim3(256), 0, stream, x, w1, qkv);
  hipLaunchKernelGGL(kb_qk,   dim3(2048), dim3(256), 0, stream, qkv, wd, gp);
  hipLaunchKernelGGL(kb_v,    dim3(3072), dim3(256), 0, stream, qkv, wd, vp);
  hipLaunchKernelGGL(kd_attn, dim3(64),   dim3(64),  0, stream, gp, wp, Mmat);
  hipLaunchKernelGGL(ke_out,  dim3(2048), dim3(256), 0, stream, vp, Mmat, (float*)d_out);
}